// Round 7
// baseline (697.943 us; speedup 1.0000x reference)
//
#include <hip/hip_runtime.h>

// RNN_64072322122514: B=4096, T=2048, F=8, H=32, O=8 Elman RNN, all fp32 I/O.
//   h_t = tanh(x_t @ W_ih^T + b_ih + b_hh + h_{t-1} @ W_hh^T);  y = h_T @ W_out^T + b_out
//
// R6 post-mortem (430 us, VALUBusy 63%, Occ 20.5%): VALU-issue-bound (159
// issue-cyc/wave-step at 2 waves/SIMD) + a chain still holding TWO LDS-pipe
// latencies (b128 gather + ds_swizzle reduce). R7:
//   - 1 row/wave, 4-way k-split in QUADS: lane=(g=lane>>2 -> dims {2g,2g+1},
//     c=lane&3 -> k-quarter [8c,8c+8), f-pair {2c,2c+1}). 4096 waves =
//     4 waves/SIMD (Occ ~40%), 2x chain coverage.
//   - gather = ONE ds_read_b128/lane (its 16-B k-quarter of the row's 64-B
//     fp16 h). 16 lanes/chunk same-address -> broadcast, conflict-free.
//   - cross-lane reduce on the VALU via DPP quad_perm butterfly (0xB1, 0x4E):
//     ~12 cyc, replaces the ~120-cyc swizzle round trip. Chain ~180 cyc.
//   - bias pre-divided by 4: the butterfly sums it back to 1x for free.
//   - xp FMAs use only prefetched x regs -> scheduled before the LDS wait.
//   - h fp16 in LDS (validated R6), partial sums + reduce all fp32.
//   - weights pre-scaled by 2*log2e; tanh = 1 - 2*rcp(exp2(s)+1).

typedef _Float16 h2v __attribute__((ext_vector_type(2)));

static constexpr int T_STEPS = 2048;
static constexpr int FDIM    = 8;
static constexpr int HDIM    = 32;
static constexpr int ODIM    = 8;
static constexpr int ROWS_PER_BLOCK = 4;    // 4 waves x 1 row
static constexpr int GROUP   = 8;           // steps per prefetch group
static constexpr int NGROUP  = T_STEPS / GROUP;   // 256 (even)

__device__ __forceinline__ float fdot2(h2v a, h2v b, float c) {
    return __builtin_amdgcn_fdot2(a, b, c, false);
}
__device__ __forceinline__ h2v bch(unsigned u) {
    return __builtin_bit_cast(h2v, u);
}

// quad butterfly add stages: quad_perm{1,0,3,2}=0xB1, quad_perm{2,3,0,1}=0x4E
#define QADD(v, ctrl)                                                          \
    ((v) + __int_as_float(__builtin_amdgcn_mov_dpp(                            \
               __float_as_int(v), (ctrl), 0xF, 0xF, true)))

__global__ __launch_bounds__(256, 4) void rnn_scan_kernel(
    const float* __restrict__ x,      // [B, T, F]
    const float* __restrict__ W_ih,   // [H, F]
    const float* __restrict__ W_hh,   // [H, H]
    const float* __restrict__ b_ih,   // [H]
    const float* __restrict__ b_hh,   // [H]
    const float* __restrict__ W_out,  // [O, H]
    const float* __restrict__ b_out,  // [O]
    float* __restrict__ out)          // [1, B, O]
{
    const float K = 2.8853900817779268f;  // 2*log2(e)
    const int tid  = threadIdx.x;
    const int lane = tid & 63;
    const int wave = tid >> 6;
    const int g    = lane >> 2;           // dim-pair 0..15: dims {2g, 2g+1}
    const int c    = lane & 3;            // k-quarter / f-pair index
    const long long b = (long long)blockIdx.x * ROWS_PER_BLOCK + wave;
    const int d0 = 2 * g, d1 = 2 * g + 1;

    __shared__ _Float16 hsh[ROWS_PER_BLOCK][HDIM];   // 256 B

    // ---- resident weights (fp16 W_hh quarter-rows, pre-scaled by K) ----
    h2v w0[4], w1[4];                     // dims d0/d1, k in [8c, 8c+8)
    const float* whr0 = W_hh + d0 * HDIM + 8 * c;
    const float* whr1 = W_hh + d1 * HDIM + 8 * c;
#pragma unroll
    for (int j = 0; j < 4; ++j) {
        h2v a; a[0] = (_Float16)(whr0[2 * j] * K); a[1] = (_Float16)(whr0[2 * j + 1] * K);
        w0[j] = a;
        h2v e; e[0] = (_Float16)(whr1[2 * j] * K); e[1] = (_Float16)(whr1[2 * j + 1] * K);
        w1[j] = e;
    }
    // xp weights for f-pair {2c, 2c+1}, both dims (fp32, K-scaled)
    const float wx00 = W_ih[d0 * FDIM + 2 * c]     * K;
    const float wx01 = W_ih[d0 * FDIM + 2 * c + 1] * K;
    const float wx10 = W_ih[d1 * FDIM + 2 * c]     * K;
    const float wx11 = W_ih[d1 * FDIM + 2 * c + 1] * K;
    // bias/4: the quad butterfly sums 4 copies back to 1x
    const float bias0 = (b_ih[d0] + b_hh[d0]) * K * 0.25f;
    const float bias1 = (b_ih[d1] + b_hh[d1]) * K * 0.25f;

    hsh[wave][d0 + (c & 1)] = (_Float16)0.0f;   // h_0 = 0 (covers all 32 dims)

    const uint4* hq = reinterpret_cast<const uint4*>(&hsh[wave][0]) + c;
    _Float16* hw = &hsh[wave][d0 + (c & 1)];
    const float2* xv = reinterpret_cast<const float2*>(x + (size_t)b * T_STEPS * FDIM);
    // x element for (step t, f-pair c) = xv[t*4 + c]

#define LOADG(buf, gi)                                                         \
    {                                                                          \
        const int base = (gi) * (GROUP * 4) + c;                               \
        _Pragma("unroll")                                                      \
        for (int k = 0; k < GROUP; ++k) buf[k] = xv[base + 4 * k];             \
    }                                                                          \
    asm volatile("" ::: "memory");

#define STEP(xr)                                                               \
    {                                                                          \
        float a0 = bias0, a1 = bias1;                                          \
        /* xp first: depends only on prefetched regs (off the LDS chain) */    \
        a0 = fmaf(wx00, xr.x, a0);  a1 = fmaf(wx10, xr.x, a1);                 \
        a0 = fmaf(wx01, xr.y, a0);  a1 = fmaf(wx11, xr.y, a1);                 \
        uint4 u = hq[0];                                                       \
        a0 = fdot2(w0[0], bch(u.x), a0);  a1 = fdot2(w1[0], bch(u.x), a1);     \
        a0 = fdot2(w0[1], bch(u.y), a0);  a1 = fdot2(w1[1], bch(u.y), a1);     \
        a0 = fdot2(w0[2], bch(u.z), a0);  a1 = fdot2(w1[2], bch(u.z), a1);     \
        a0 = fdot2(w0[3], bch(u.w), a0);  a1 = fdot2(w1[3], bch(u.w), a1);     \
        /* quad butterfly: all 4 lanes get both dims' full sums (fp32) */      \
        a0 = QADD(a0, 0xB1);  a1 = QADD(a1, 0xB1);                             \
        a0 = QADD(a0, 0x4E);  a1 = QADD(a1, 0x4E);                             \
        float s = (c & 1) ? a1 : a0;                                           \
        float e = __builtin_amdgcn_exp2f(s);                                   \
        float rc = __builtin_amdgcn_rcpf(e + 1.0f);                            \
        *hw = (_Float16)fmaf(-2.0f, rc, 1.0f);                                 \
    }

#define STEPS(buf)                                                             \
    STEP(buf[0]) STEP(buf[1]) STEP(buf[2]) STEP(buf[3])                        \
    STEP(buf[4]) STEP(buf[5]) STEP(buf[6]) STEP(buf[7])

    float2 bufA[GROUP], bufB[GROUP];
    LOADG(bufA, 0)

    for (int gi = 0; gi < NGROUP; gi += 2) {
        const int g1 = (gi + 1 < NGROUP) ? (gi + 1) : gi;
        LOADG(bufB, g1)
        STEPS(bufA)
        const int g2 = (gi + 2 < NGROUP) ? (gi + 2) : gi;
        LOADG(bufA, g2)
        STEPS(bufB)
    }
#undef STEPS
#undef STEP
#undef LOADG

    // ---- epilogue: y = h_T @ W_out^T + b_out ----
    __syncthreads();
    if (tid < ROWS_PER_BLOCK * ODIM) {   // 32 threads
        const int rr = tid >> 3;
        const int o  = tid & 7;
        float acc = b_out[o];
#pragma unroll
        for (int j = 0; j < HDIM; ++j)
            acc = fmaf((float)hsh[rr][j], W_out[o * HDIM + j], acc);
        out[((long long)blockIdx.x * ROWS_PER_BLOCK + rr) * ODIM + o] = acc;
    }
}

extern "C" void kernel_launch(void* const* d_in, const int* in_sizes, int n_in,
                              void* d_out, int out_size, void* d_ws, size_t ws_size,
                              hipStream_t stream) {
    const float* x     = (const float*)d_in[0];
    const float* W_ih  = (const float*)d_in[1];
    const float* W_hh  = (const float*)d_in[2];
    const float* b_ih  = (const float*)d_in[3];
    const float* b_hh  = (const float*)d_in[4];
    const float* W_out = (const float*)d_in[5];
    const float* b_out = (const float*)d_in[6];

    const int B = in_sizes[0] / (T_STEPS * FDIM);   // 4096
    const int grid = B / ROWS_PER_BLOCK;            // 1024 blocks = 4/CU

    rnn_scan_kernel<<<grid, 256, 0, stream>>>(
        x, W_ih, W_hh, b_ih, b_hh, W_out, b_out, (float*)d_out);
}